// Round 4
// baseline (411.608 us; speedup 1.0000x reference)
//
#include <hip/hip_runtime.h>

typedef unsigned int uint;
typedef float f32x2 __attribute__((ext_vector_type(2)));

#define N_NODES 100000
#define N_EDGES 3200000
#define IN_CH 128
#define HID 64
#define N_GRAPHS 512
#define EPB 4096                                   // edges per block (multisplit)
#define NBLK ((N_EDGES + EPB - 1) / EPB)           // 782
#define GBITS 6
#define GNODES 64                                  // nodes per bucket
#define NB 1563                                    // ceil(100000/64)
#define CAP 2560                                   // bucket capacity (mean 2048, +11 sigma)

#define SCALE_F 262144.0f                          // 2^18 fixed-point scale
#define INV_SCALE_F 3.814697265625e-06f            // 2^-18

// ---------------------------------------------------------------------------
// bf16 helpers. Interleaved layout: row = 32 uints, uint j = (ch j | ch j+32<<16).
__device__ __forceinline__ uint f2bf1(float f) {
    union { float f; uint i; } v; v.f = f;
    return (v.i + 0x7fffu + ((v.i >> 16) & 1u)) >> 16;    // RNE
}
__device__ __forceinline__ uint pack2(float lo, float hi) {
    return f2bf1(lo) | (f2bf1(hi) << 16);
}
__device__ __forceinline__ float2 ub2(uint u) {
    union { uint i; float f; } a, b;
    a.i = u << 16; b.i = u & 0xffff0000u;
    return make_float2(a.f, b.f);
}
__device__ __forceinline__ f32x2 up2(uint u) {
    union { uint i; float f; } lo, hi;
    lo.i = u << 16; hi.i = u & 0xffff0000u;
    f32x2 r; r.x = lo.f; r.y = hi.f;
    return r;
}

// ---------------------------------------------------------------------------
// One-pass multisplit into 64-node buckets: register-cached edges, LDS
// histogram, one padded global atomic per (bucket, block), scatter.
__global__ __launch_bounds__(256) void scatter_kernel(const int* __restrict__ src,
                                                      const int* __restrict__ dst,
                                                      int* __restrict__ bcnt,
                                                      uint* __restrict__ pairs) {
    __shared__ int h[4 * NB];
    __shared__ int start[NB];
    __shared__ int cur[NB];
    int t = threadIdx.x;
    int base = blockIdx.x * EPB;

    int rs[16], rd[16];
#pragma unroll
    for (int j = 0; j < 16; ++j) {
        int e = base + j * 256 + t;
        if (e < N_EDGES) { rs[j] = src[e]; rd[j] = dst[e]; }
        else rd[j] = -1;
    }
    for (int i = t; i < 4 * NB; i += 256) h[i] = 0;
    __syncthreads();
    int w = t >> 6;
#pragma unroll
    for (int j = 0; j < 16; ++j)
        if (rd[j] >= 0) atomicAdd(&h[w * NB + (rd[j] >> GBITS)], 1);
    __syncthreads();
    for (int b = t; b < NB; b += 256) {
        int tot = h[b] + h[NB + b] + h[2 * NB + b] + h[3 * NB + b];
        start[b] = tot ? atomicAdd(&bcnt[b * 16], tot) : 0;
        cur[b] = 0;
    }
    __syncthreads();
#pragma unroll
    for (int j = 0; j < 16; ++j) {
        if (rd[j] >= 0) {
            int b = rd[j] >> GBITS;
            int r = atomicAdd(&cur[b], 1);
            pairs[(size_t)b * CAP + start[b] + r] =
                ((uint)(rd[j] & (GNODES - 1)) << 24) | (uint)rs[j];   // src < 2^17
        }
    }
}

// ---------------------------------------------------------------------------
// Slim degree pass: per-bucket wave-replicated LDS histogram -> dis.
__global__ __launch_bounds__(256) void degree_kernel(const uint* __restrict__ pairs,
                                                     const int* __restrict__ bcnt,
                                                     float* __restrict__ dis) {
    __shared__ int h4[4 * GNODES];
    int b = blockIdx.x;
    int t = threadIdx.x;
    int w = t >> 6;
    int e0 = b * CAP;
    int e1 = e0 + bcnt[b * 16];

    for (int i = t; i < 4 * GNODES; i += 256) h4[i] = 0;
    __syncthreads();
    int* hw = &h4[w * GNODES];
    int e = e0 + t;
    for (; e + 768 < e1; e += 1024) {
        uint p0 = pairs[e], p1 = pairs[e + 256], p2 = pairs[e + 512], p3 = pairs[e + 768];
        atomicAdd(&hw[p0 >> 24], 1);
        atomicAdd(&hw[p1 >> 24], 1);
        atomicAdd(&hw[p2 >> 24], 1);
        atomicAdd(&hw[p3 >> 24], 1);
    }
    for (; e < e1; e += 256)
        atomicAdd(&hw[pairs[e] >> 24], 1);
    __syncthreads();
    if (t < GNODES) {
        int v = h4[t] + h4[GNODES + t] + h4[2 * GNODES + t] + h4[3 * GNODES + t];
        int n = b * GNODES + t;
        if (n < N_NODES) dis[n] = rsqrtf((float)v + 1.0f);
    }
}

// ---------------------------------------------------------------------------
// GEMM1: Y[M,64](bf16 interleaved) = (X[M,128] @ W[128,64]) * dis.  X fp32.
__global__ __launch_bounds__(256) void gemm1_kernel(const float* __restrict__ X,
                                                    const float* __restrict__ W,
                                                    const float* __restrict__ dis,
                                                    uint* __restrict__ Y) {
    __shared__ float Wl[IN_CH * 64];
    __shared__ float Xs[128 * 33];
    int t = threadIdx.x;
    for (int idx = t; idx < IN_CH * 64; idx += 256) Wl[idx] = W[idx];

    int r0 = (t >> 3) * 4;
    int c0 = (t & 7) * 4;                 // channels c0..c0+3 and c0+32..c0+35
    int rowBase = blockIdx.x * 128;

    float acc[4][8];
#pragma unroll
    for (int a = 0; a < 4; ++a)
#pragma unroll
        for (int c = 0; c < 8; ++c) acc[a][c] = 0.f;

    int srow = t >> 1;
    int shh = (t & 1) * 16;
    bool sok = (rowBase + srow) < N_NODES;
    const float* xbase = X + (size_t)(rowBase + srow) * IN_CH + shh;

    float4 nx[4];
#pragma unroll
    for (int f = 0; f < 4; ++f)
        nx[f] = sok ? *reinterpret_cast<const float4*>(xbase + f * 4)
                    : make_float4(0.f, 0.f, 0.f, 0.f);

    for (int kc = 0; kc < IN_CH; kc += 32) {
        if (kc) __syncthreads();
#pragma unroll
        for (int f = 0; f < 4; ++f) {
            int o = srow * 33 + shh + f * 4;
            Xs[o] = nx[f].x; Xs[o + 1] = nx[f].y; Xs[o + 2] = nx[f].z; Xs[o + 3] = nx[f].w;
        }
        __syncthreads();
        if (kc + 32 < IN_CH) {
#pragma unroll
            for (int f = 0; f < 4; ++f)
                nx[f] = sok ? *reinterpret_cast<const float4*>(xbase + kc + 32 + f * 4)
                            : make_float4(0.f, 0.f, 0.f, 0.f);
        }
#pragma unroll
        for (int kk = 0; kk < 32; ++kk) {
            const float4 wa = *reinterpret_cast<const float4*>(&Wl[(kc + kk) * 64 + c0]);
            const float4 wb = *reinterpret_cast<const float4*>(&Wl[(kc + kk) * 64 + c0 + 32]);
            float xr[4];
#pragma unroll
            for (int a = 0; a < 4; ++a) xr[a] = Xs[(r0 + a) * 33 + kk];
#pragma unroll
            for (int a = 0; a < 4; ++a) {
                acc[a][0] += xr[a] * wa.x; acc[a][1] += xr[a] * wa.y;
                acc[a][2] += xr[a] * wa.z; acc[a][3] += xr[a] * wa.w;
                acc[a][4] += xr[a] * wb.x; acc[a][5] += xr[a] * wb.y;
                acc[a][6] += xr[a] * wb.z; acc[a][7] += xr[a] * wb.w;
            }
        }
    }
#pragma unroll
    for (int a = 0; a < 4; ++a) {
        int row = rowBase + r0 + a;
        if (row < N_NODES) {
            float d = dis[row];
            uint4 o;
            o.x = pack2(acc[a][0] * d, acc[a][4] * d);
            o.y = pack2(acc[a][1] * d, acc[a][5] * d);
            o.z = pack2(acc[a][2] * d, acc[a][6] * d);
            o.w = pack2(acc[a][3] * d, acc[a][7] * d);
            *reinterpret_cast<uint4*>(Y + (size_t)row * 32 + (t & 7) * 4) = o;
        }
    }
}

// ---------------------------------------------------------------------------
// GEMM2: Y[M,64](bf16 interleaved) = (relu(X)[M,64] @ W[64,64]) * dis.
// X bf16 interleaved; single-staged (all 64 ch in LDS), one K loop.
__global__ __launch_bounds__(256) void gemm2_kernel(const uint* __restrict__ X,
                                                    const float* __restrict__ W,
                                                    const float* __restrict__ dis,
                                                    uint* __restrict__ Y) {
    __shared__ float Wl[HID * 64];       // 16 KB
    __shared__ float Xs[128 * 65];       // 33.3 KB
    int t = threadIdx.x;
    for (int idx = t; idx < HID * 64; idx += 256) Wl[idx] = W[idx];

    int r0 = (t >> 3) * 4;
    int c0 = (t & 7) * 4;
    int rowBase = blockIdx.x * 128;

    {   // stage: thread (srow, half) unpacks uints half*16..+15 -> ch c and c+32
        int srow = t >> 1, half = t & 1;
        bool sok = (rowBase + srow) < N_NODES;
        float* xs = &Xs[srow * 65 + half * 16];
        if (sok) {
            const uint* xb = X + (size_t)(rowBase + srow) * 32 + half * 16;
            uint4 u0 = *reinterpret_cast<const uint4*>(xb);
            uint4 u1 = *reinterpret_cast<const uint4*>(xb + 4);
            uint4 u2 = *reinterpret_cast<const uint4*>(xb + 8);
            uint4 u3 = *reinterpret_cast<const uint4*>(xb + 12);
            uint us[16] = {u0.x, u0.y, u0.z, u0.w, u1.x, u1.y, u1.z, u1.w,
                           u2.x, u2.y, u2.z, u2.w, u3.x, u3.y, u3.z, u3.w};
#pragma unroll
            for (int k = 0; k < 16; ++k) {
                float2 f = ub2(us[k]);
                xs[k]      = fmaxf(f.x, 0.f);
                xs[32 + k] = fmaxf(f.y, 0.f);
            }
        } else {
#pragma unroll
            for (int k = 0; k < 16; ++k) { xs[k] = 0.f; xs[32 + k] = 0.f; }
        }
    }
    __syncthreads();

    float acc[4][8];
#pragma unroll
    for (int a = 0; a < 4; ++a)
#pragma unroll
        for (int c = 0; c < 8; ++c) acc[a][c] = 0.f;

#pragma unroll 4
    for (int kk = 0; kk < HID; ++kk) {
        const float4 wa = *reinterpret_cast<const float4*>(&Wl[kk * 64 + c0]);
        const float4 wb = *reinterpret_cast<const float4*>(&Wl[kk * 64 + c0 + 32]);
        float xr[4];
#pragma unroll
        for (int a = 0; a < 4; ++a) xr[a] = Xs[(r0 + a) * 65 + kk];
#pragma unroll
        for (int a = 0; a < 4; ++a) {
            acc[a][0] += xr[a] * wa.x; acc[a][1] += xr[a] * wa.y;
            acc[a][2] += xr[a] * wa.z; acc[a][3] += xr[a] * wa.w;
            acc[a][4] += xr[a] * wb.x; acc[a][5] += xr[a] * wb.y;
            acc[a][6] += xr[a] * wb.z; acc[a][7] += xr[a] * wb.w;
        }
    }
#pragma unroll
    for (int a = 0; a < 4; ++a) {
        int row = rowBase + r0 + a;
        if (row < N_NODES) {
            float d = dis[row];
            uint4 o;
            o.x = pack2(acc[a][0] * d, acc[a][4] * d);
            o.y = pack2(acc[a][1] * d, acc[a][5] * d);
            o.z = pack2(acc[a][2] * d, acc[a][6] * d);
            o.w = pack2(acc[a][3] * d, acc[a][7] * d);
            *reinterpret_cast<uint4*>(Y + (size_t)row * 32 + (t & 7) * 4) = o;
        }
    }
}

// ---------------------------------------------------------------------------
// Bucket gather with NATIVE int LDS atomics (ds_add_u32), fixed-point 2^18.
// One block per 64-node bucket; acc[n][j] = scaled sum of channel j (16 KB).
// Each half-wave streams edges (4-deep unroll); lane l handles uint col l
// of the src row -> ds_add to [n][l] (bank l) and [n][l+32] (bank l) --
// 2-way across half-waves = free. Init = scaled self term.
// POOL=false: epilogue writes bf16 B row.  POOL=true: epilogue fuses
// global_mean_pool (relu + segment accumulate into sums/cnt), B not written.
template <bool POOL>
__global__ __launch_bounds__(512) void gather_ds_kernel(const uint* __restrict__ pairs,
                                                        const int* __restrict__ bcnt,
                                                        const float* __restrict__ dis,
                                                        const float* __restrict__ bias,
                                                        const uint* __restrict__ A,
                                                        uint* __restrict__ B,
                                                        const int* __restrict__ batch,
                                                        float* __restrict__ sums,
                                                        float* __restrict__ cnt) {
    __shared__ int acc[GNODES * 64];     // 16 KB
    int b = blockIdx.x;
    int t = threadIdx.x;
    int e0 = b * CAP;
    int e1 = e0 + bcnt[b * 16];

    {   // init with scaled self term: 8 threads/node, 4+4 uint cols each
        int n = t >> 3, j0 = (t & 7) * 4;
        int gn = b * GNODES + n;
        int* ar = acc + n * 64 + j0;
        if (gn < N_NODES) {
            uint4 u = *reinterpret_cast<const uint4*>(A + (size_t)gn * 32 + j0);
            uint us[4] = {u.x, u.y, u.z, u.w};
            int lo[4], hi[4];
#pragma unroll
            for (int k = 0; k < 4; ++k) {
                f32x2 f = up2(us[k]) * SCALE_F;
                lo[k] = (int)f.x; hi[k] = (int)f.y;
            }
            *reinterpret_cast<int4*>(ar)      = make_int4(lo[0], lo[1], lo[2], lo[3]);
            *reinterpret_cast<int4*>(ar + 32) = make_int4(hi[0], hi[1], hi[2], hi[3]);
        } else {
            *reinterpret_cast<int4*>(ar)      = make_int4(0, 0, 0, 0);
            *reinterpret_cast<int4*>(ar + 32) = make_int4(0, 0, 0, 0);
        }
    }
    __syncthreads();

    int hw = t >> 5;            // half-wave id 0..15 (one edge stream each)
    int l = t & 31;             // uint col within row -> channels l, l+32
    int e = e0 + hw;
    for (; e + 48 < e1; e += 64) {
        uint p0 = pairs[e];
        uint p1 = pairs[e + 16];
        uint p2 = pairs[e + 32];
        uint p3 = pairs[e + 48];
        uint u0 = A[(size_t)(p0 & 0xFFFFFFu) * 32 + l];
        uint u1 = A[(size_t)(p1 & 0xFFFFFFu) * 32 + l];
        uint u2 = A[(size_t)(p2 & 0xFFFFFFu) * 32 + l];
        uint u3 = A[(size_t)(p3 & 0xFFFFFFu) * 32 + l];
        int* a0 = acc + (p0 >> 24) * 64 + l;
        int* a1 = acc + (p1 >> 24) * 64 + l;
        int* a2 = acc + (p2 >> 24) * 64 + l;
        int* a3 = acc + (p3 >> 24) * 64 + l;
        f32x2 f0 = up2(u0) * SCALE_F;
        f32x2 f1 = up2(u1) * SCALE_F;
        f32x2 f2 = up2(u2) * SCALE_F;
        f32x2 f3 = up2(u3) * SCALE_F;
        atomicAdd(a0, (int)f0.x); atomicAdd(a0 + 32, (int)f0.y);
        atomicAdd(a1, (int)f1.x); atomicAdd(a1 + 32, (int)f1.y);
        atomicAdd(a2, (int)f2.x); atomicAdd(a2 + 32, (int)f2.y);
        atomicAdd(a3, (int)f3.x); atomicAdd(a3 + 32, (int)f3.y);
    }
    for (; e < e1; e += 16) {
        uint p = pairs[e];
        uint u = A[(size_t)(p & 0xFFFFFFu) * 32 + l];
        int* a = acc + (p >> 24) * 64 + l;
        f32x2 f = up2(u) * SCALE_F;
        atomicAdd(a, (int)f.x); atomicAdd(a + 32, (int)f.y);
    }
    __syncthreads();

    if (!POOL) {
        // B[n] = bf16(bias + dis[n] * acc[n] * 2^-18)
        int n = t >> 3, j0 = (t & 7) * 4;
        int gn = b * GNODES + n;
        if (gn < N_NODES) {
            float dv = dis[gn];
            const int* ar = acc + n * 64 + j0;
            uint o[4];
#pragma unroll
            for (int k = 0; k < 4; ++k) {
                float vx = bias[j0 + k]      + dv * (float)ar[k]      * INV_SCALE_F;
                float vy = bias[32 + j0 + k] + dv * (float)ar[32 + k] * INV_SCALE_F;
                o[k] = pack2(vx, vy);
            }
            *reinterpret_cast<uint4*>(B + (size_t)gn * 32 + j0) =
                make_uint4(o[0], o[1], o[2], o[3]);
        }
    } else {
        // fused global_mean_pool: half-wave hw handles 4 nodes, lane l owns
        // channels l and l+32; batch sorted -> run-length accumulate.
        int n0 = b * GNODES + hw * 4;
        if (n0 < N_NODES) {
            int n1 = min(n0 + 4, N_NODES);
            int curg = batch[n0];
            float a0 = 0.f, a1 = 0.f;
            int run = 0;
            for (int n = n0; n < n1; ++n) {
                int g = batch[n];
                if (g != curg) {
                    atomicAdd(&sums[curg * 64 + l], a0);
                    atomicAdd(&sums[curg * 64 + 32 + l], a1);
                    if (l == 0) atomicAdd(&cnt[curg], (float)run);
                    curg = g; a0 = 0.f; a1 = 0.f; run = 0;
                }
                int ln = n - b * GNODES;
                float dv = dis[n];
                float vx = bias[l]      + dv * (float)acc[ln * 64 + l]      * INV_SCALE_F;
                float vy = bias[32 + l] + dv * (float)acc[ln * 64 + 32 + l] * INV_SCALE_F;
                a0 += fmaxf(vx, 0.f);
                a1 += fmaxf(vy, 0.f);
                ++run;
            }
            atomicAdd(&sums[curg * 64 + l], a0);
            atomicAdd(&sums[curg * 64 + 32 + l], a1);
            if (l == 0) atomicAdd(&cnt[curg], (float)run);
        }
    }
}

__global__ __launch_bounds__(256) void final_kernel(const float* __restrict__ sums,
                                                    const float* __restrict__ cnt,
                                                    float* __restrict__ out) {
    int idx = blockIdx.x * 256 + threadIdx.x;
    if (idx < N_GRAPHS * 64) out[idx] = sums[idx] / fmaxf(cnt[idx >> 6], 1.0f);
}

// ---------------------------------------------------------------------------
extern "C" void kernel_launch(void* const* d_in, const int* in_sizes, int n_in,
                              void* d_out, int out_size, void* d_ws, size_t ws_size,
                              hipStream_t stream) {
    const float* x     = (const float*)d_in[0];
    const int*   edge  = (const int*)d_in[1];   // [2, E]: row0 = src, row1 = dst
    const int*   batch = (const int*)d_in[2];
    const float* W1    = (const float*)d_in[3];
    const float* b1    = (const float*)d_in[4];
    const float* W2    = (const float*)d_in[5];
    const float* b2    = (const float*)d_in[6];
    float* out = (float*)d_out;

    // workspace layout (elements)
    uint*  A     = (uint*)d_ws;                           // 3,200,000 u (bf16 A)
    uint*  B     = A + (size_t)N_NODES * 32;              // 3,200,000 u (bf16 B)
    uint*  pairs = B + (size_t)N_NODES * 32;              // NB*CAP = 4,001,280 u
    float* dis   = (float*)(pairs + (size_t)NB * CAP);    // 100,000 f
    float* sums  = dis + N_NODES;                         // 32,768 f
    float* cnt_f = sums + (size_t)N_GRAPHS * 64;          // 512 f
    int*   bcnt  = (int*)(cnt_f + N_GRAPHS);              // NB*16 = 25,008 i (padded)
    // total ~42 MB

    const int* src = edge;
    const int* dst = edge + N_EDGES;

    // zero sums + cnt + bcnt in one shot (contiguous)
    hipMemsetAsync(sums, 0, (N_GRAPHS * 64 + N_GRAPHS + NB * 16) * sizeof(float), stream);

    // bucket build: multisplit + slim degree pass (no CSR)
    scatter_kernel<<<NBLK, 256, 0, stream>>>(src, dst, bcnt, pairs);
    degree_kernel<<<NB, 256, 0, stream>>>(pairs, bcnt, dis);

    // layer 1: A = bf16((x@W1)*dis) ; B = bf16(b1 + dis*(A[i] + sum A[src]))
    gemm1_kernel<<<(N_NODES + 127) / 128, 256, 0, stream>>>(x, W1, dis, A);
    gather_ds_kernel<false><<<NB, 512, 0, stream>>>(pairs, bcnt, dis, b1, A, B,
                                                    batch, sums, cnt_f);

    // layer 2 (relu fused into GEMM2 staging); gather2 fuses the mean-pool
    gemm2_kernel<<<(N_NODES + 127) / 128, 256, 0, stream>>>(B, W2, dis, A);
    gather_ds_kernel<true><<<NB, 512, 0, stream>>>(pairs, bcnt, dis, b2, A, B,
                                                   batch, sums, cnt_f);

    final_kernel<<<(N_GRAPHS * 64 + 255) / 256, 256, 0, stream>>>(sums, cnt_f, out);
}